// Round 14
// baseline (419.274 us; speedup 1.0000x reference)
//
#include <hip/hip_runtime.h>
#include <math.h>

typedef short s16x8 __attribute__((ext_vector_type(8)));
typedef __bf16 b16x8 __attribute__((ext_vector_type(8)));
typedef float f32x4 __attribute__((ext_vector_type(4)));
typedef float f32x2 __attribute__((ext_vector_type(2)));
typedef unsigned int u32x4 __attribute__((ext_vector_type(4)));
typedef unsigned int u32x2 __attribute__((ext_vector_type(2)));

__device__ inline short f2bf(float f) {
    unsigned u = __float_as_uint(f);
    unsigned r = u + 0x7FFFu + ((u >> 16) & 1u);   // RNE
    return (short)(r >> 16);
}

// ---------------- count (CSR degree) ----------------

__global__ void count_kernel(const int* __restrict__ dst, int* __restrict__ cnt, int E) {
    int e = blockIdx.x * 256 + threadIdx.x;
    if (e < E) atomicAdd(&cnt[dst[e]], 1);
}

// ---------------- fused scan + fixup + weight conversion ----------------
// Blocks [0, SB): single-pass scan with device-scope published block totals.
// Blocks [SB, ...): Wt1/Wt2 frag-layout conversion (1024-thread roles).
// Wt chunk layout: [c = k0/32][b = n0/128][nt 0..7][lane 0..63][j 0..7]
//   value = W[c*32 + (lane>>4)*8 + j][b*128 + nt*16 + (lane&15)]

__device__ inline void make_wt_elem(const float* __restrict__ W, short* __restrict__ Wt,
                                    int K, int N, int idx) {
    int NB = N >> 7;
    int j = idx & 7;
    int l = (idx >> 3) & 63;
    int nt = (idx >> 9) & 7;
    int rest = idx >> 12;
    int b = rest % NB;
    int c = rest / NB;
    int k = c * 32 + (l >> 4) * 8 + j;
    int n = b * 128 + nt * 16 + (l & 15);
    Wt[idx] = f2bf(W[(size_t)k * N + n]);
}

__global__ __launch_bounds__(1024) void scanfix_kernel(
        const int* __restrict__ cnt, int* __restrict__ rp, int* __restrict__ cursor,
        float* __restrict__ dinv, int* __restrict__ bsum, int n, int E, int SB,
        const float* __restrict__ W1, short* __restrict__ Wt1,
        const float* __restrict__ W2, short* __restrict__ Wt2, int w1b) {
    int tid = threadIdx.x;
    if (blockIdx.x >= SB) {                    // ---- weight-conversion role ----
        int b = blockIdx.x - SB;
        if (b < w1b) {
            int idx = b * 1024 + tid;
            make_wt_elem(W1, Wt1, 768, 256, idx);
        } else {
            int idx = (b - w1b) * 1024 + tid;
            make_wt_elem(W2, Wt2, 256, 128, idx);
        }
        return;
    }

    // ---- scan role ----
    __shared__ int sdata[1024];
    __shared__ int parts[64];
    __shared__ int carry_s;
    int i = blockIdx.x * 1024 + tid;
    int v = (i < n) ? cnt[i] : 0;
    sdata[tid] = v;
    __syncthreads();
    for (int off = 1; off < 1024; off <<= 1) {
        int t = 0;
        if (tid >= off) t = sdata[tid - off];
        __syncthreads();
        sdata[tid] += t;
        __syncthreads();
    }
    if (tid == 1023)
        __hip_atomic_store(&bsum[blockIdx.x], sdata[1023] + 1,
                           __ATOMIC_RELEASE, __HIP_MEMORY_SCOPE_AGENT);
    int part = 0;
    if (tid < blockIdx.x) {                    // lanes 0..47 of wave 0 (SB <= 49)
        int b;
        while ((b = __hip_atomic_load(&bsum[tid], __ATOMIC_ACQUIRE,
                                      __HIP_MEMORY_SCOPE_AGENT)) == 0) {}
        part = b - 1;
    }
    if (tid < 64) parts[tid] = part;
    __syncthreads();
    if (tid == 0) {
        int c = 0;
        for (int k = 0; k < 64; ++k) c += parts[k];
        carry_s = c;
    }
    __syncthreads();
    int r = sdata[tid] - v + carry_s;          // exclusive prefix + carry
    if (i < n) {
        rp[i] = r;
        cursor[i] = r;
        dinv[i] = rsqrtf((float)cnt[i] + 1.0f);
    }
    if (i == 0) rp[n] = E;
}

// ---------------- fused GEMM1 + fill (interleaved roles) ----------------
// Roles interleaved by block index via Bresenham proportional mapping.

__global__ __launch_bounds__(256, 3) void gemm1_fill_kernel(
        const float* __restrict__ x, const short* __restrict__ Wt,
        unsigned char* __restrict__ h8, int M, int G1B, int FB,
        const int* __restrict__ src, const int* __restrict__ dst,
        int* __restrict__ cursor, const float* __restrict__ dinv,
        int2* __restrict__ ecw, int E) {
    constexpr int KC = 24;                     // 768 / 32
    constexpr int RT = 2;                      // row-tiles -> 32 rows per block
    constexpr int O = KC * 4;                  // 96 octets (8 k-elems) per row
    constexpr int F = KC * RT * 64 / 256;      // 12 frags staged per thread

    __shared__ s16x8 As[KC * RT * 64];         // 48 KB bf16, fragment-ready

    const int tid = threadIdx.x;
    const int total = G1B + FB;
    const long long bi = (long long)blockIdx.x;
    const int fid  = (int)(bi * FB / total);
    const int fid1 = (int)((bi + 1) * FB / total);

    if (fid1 > fid) {                          // ---- fill role ----
        int e = fid * 256 + tid;
        if (e < E) {
            int d = dst[e];
            int s = src[e];
            int p = atomicAdd(&cursor[d], 1);
            ecw[p] = make_int2(s, __float_as_int(dinv[s] * dinv[d]));
        }
        return;
    }
    const int gid = blockIdx.x - fid;          // gemm1 block id, 0..G1B-1

    // ---- gemm1 role ----
    const int m0 = gid * (RT * 16);

    // stage: load fp32 pairs, truncation-pack to bf16
    s16x8 v[F];
#pragma unroll
    for (int i = 0; i < F; ++i) {
        int idx = i * 256 + tid;
        int r = idx / O;
        int o = idx - r * O;
        int row = m0 + r;
        if (row >= M) row = M - 1;
        const float4* fp = (const float4*)(x + (size_t)row * 768 + o * 8);
        float4 f0 = fp[0];
        float4 f1 = fp[1];
        u32x4 pk;
        pk.x = (__float_as_uint(f0.x) >> 16) | (__float_as_uint(f0.y) & 0xFFFF0000u);
        pk.y = (__float_as_uint(f0.z) >> 16) | (__float_as_uint(f0.w) & 0xFFFF0000u);
        pk.z = (__float_as_uint(f1.x) >> 16) | (__float_as_uint(f1.y) & 0xFFFF0000u);
        pk.w = (__float_as_uint(f1.z) >> 16) | (__float_as_uint(f1.w) & 0xFFFF0000u);
        v[i] = __builtin_bit_cast(s16x8, pk);
    }
#pragma unroll
    for (int i = 0; i < F; ++i) {
        int idx = i * 256 + tid;
        int r = idx / O;
        int o = idx - r * O;
        int c = o >> 2, q = o & 3;
        int slot = q * 16 + (((r & 15) + q + ((c & 3) << 2)) & 15);
        As[(c * RT + (r >> 4)) * 64 + slot] = v[i];
    }
    __syncthreads();

    const int lane = tid & 63;
    const int wave = tid >> 6;
    const int b128 = wave >> 1;                // 128-col B block
    const int nt0 = (wave & 1) * 4;            // first 16-col tile inside it
    const int q = lane >> 4;
    const int rl = lane & 15;
    const s16x8* wt = (const s16x8*)Wt;

    f32x4 acc[RT][4];
#pragma unroll
    for (int i = 0; i < RT; ++i)
#pragma unroll
        for (int j = 0; j < 4; ++j)
            acc[i][j] = (f32x4){0.f, 0.f, 0.f, 0.f};

#pragma unroll 4
    for (int c = 0; c < KC; ++c) {
        int slot = q * 16 + ((rl + q + ((c & 3) << 2)) & 15);
        b16x8 areg[RT], breg[4];
#pragma unroll
        for (int i = 0; i < RT; ++i)
            areg[i] = __builtin_bit_cast(b16x8, As[(c * RT + i) * 64 + slot]);
        size_t bb = (size_t)(c * 2 + b128) * 512 + nt0 * 64 + lane;
#pragma unroll
        for (int j = 0; j < 4; ++j)
            breg[j] = __builtin_bit_cast(b16x8, wt[bb + j * 64]);
#pragma unroll
        for (int i = 0; i < RT; ++i)
#pragma unroll
            for (int j = 0; j < 4; ++j)
                acc[i][j] = __builtin_amdgcn_mfma_f32_16x16x32_bf16(areg[i], breg[j], acc[i][j], 0, 0, 0);
    }

    const int quad = lane >> 4;
    const int nl = lane & 15;
#pragma unroll
    for (int i = 0; i < RT; ++i) {
        int rbase = m0 + i * 16 + quad * 4;
#pragma unroll
        for (int j = 0; j < 4; ++j) {
            int col = wave * 64 + j * 16 + nl;
#pragma unroll
            for (int r = 0; r < 4; ++r) {
                int row = rbase + r;
                if (row < M) {
                    unsigned u = __builtin_amdgcn_cvt_pk_fp8_f32(acc[i][j][r], acc[i][j][r], 0, false);
                    h8[(size_t)row * 256 + col] = (unsigned char)(u & 0xFF);
                }
            }
        }
    }
}

// ---------------- fused layer-1 aggregation + layer-2 GEMM ----------------
// Block = 16 nodes (4 waves x 4 sequential nodes). Phase 1 (per node): champion
// 4-edge-parallel fp8 gather + xor reduce + bias/relu, pack a1 to bf16 and write
// into the PROVEN frag-ready swizzled LDS layout (gemm_panel staging, RT=1:
// frag (r, octet o): c=o>>2, q=o&3, slot = q*16 + ((r + q + ((c&3)<<2)) & 15);
// eg0 lanes write even octets 2ch, eg1 odd octets 2ch+1). One barrier.
// Phase 2: h2[16x128] = a1 @ Wt2 via 16 MFMAs/wave (wave w -> col tiles 2w, 2w+1),
// fp8 epilogue. Eliminates the separate gemm_panel launch AND the hB buffer.

__global__ __launch_bounds__(256) void agg256_g2_kernel(const unsigned char* __restrict__ h8,
                                                        const int* __restrict__ rp,
                                                        const int2* __restrict__ ecw,
                                                        const float* __restrict__ dinv,
                                                        const float* __restrict__ bias,
                                                        const short* __restrict__ Wt2,
                                                        unsigned char* __restrict__ h2, int n) {
    __shared__ s16x8 As[8 * 64];               // 16 rows x 256 ch bf16, frag-ready (8 KB)

    const int tid = threadIdx.x;
    const int lane = tid & 63;
    const int wave = tid >> 6;
    const int eg = lane >> 4;                    // edge slot 0..3
    const int ch = lane & 15;                    // 16-channel chunk
    const int nb0 = blockIdx.x * 16;

    for (int t = 0; t < 4; ++t) {
        const int r = wave * 4 + t;              // row in block 0..15
        const int node = nb0 + r;
        float acc[16];
#pragma unroll
        for (int k = 0; k < 16; ++k) acc[k] = 0.f;

        if (node < n) {
            float di = dinv[node];
            {
                u32x4 v = *(const u32x4*)(h8 + (size_t)node * 256 + ch * 16);
                float ws = (eg == 0) ? di * di : 0.f;    // self term counted once
#pragma unroll
                for (int u = 0; u < 4; ++u) {
                    f32x2 lo = __builtin_amdgcn_cvt_pk_f32_fp8(v[u], false);
                    f32x2 hi = __builtin_amdgcn_cvt_pk_f32_fp8(v[u], true);
                    acc[u * 4 + 0] = ws * lo.x; acc[u * 4 + 1] = ws * lo.y;
                    acc[u * 4 + 2] = ws * hi.x; acc[u * 4 + 3] = ws * hi.y;
                }
            }
            int e0 = rp[node], e1 = rp[node + 1];
            for (int base = e0; base < e1; base += 64) {
                int idx = base + lane;
                int2 er = (idx < e1) ? ecw[idx] : make_int2(0, 0);
                int sb = er.x;
                float wb = __int_as_float(er.y);
                int cnt = e1 - base; if (cnt > 64) cnt = 64;
#pragma unroll 4
                for (int i = 0; i < cnt; i += 4) {
                    int s = __shfl(sb, i + eg, 64);   // i+eg <= 63 (i step 4, i<=60)
                    float w = __shfl(wb, i + eg, 64);
                    u32x4 v = *(const u32x4*)(h8 + (size_t)s * 256 + ch * 16);
#pragma unroll
                    for (int u = 0; u < 4; ++u) {
                        f32x2 lo = __builtin_amdgcn_cvt_pk_f32_fp8(v[u], false);
                        f32x2 hi = __builtin_amdgcn_cvt_pk_f32_fp8(v[u], true);
                        acc[u * 4 + 0] += w * lo.x; acc[u * 4 + 1] += w * lo.y;
                        acc[u * 4 + 2] += w * hi.x; acc[u * 4 + 3] += w * hi.y;
                    }
                }
            }
            // combine the 4 edge slots
#pragma unroll
            for (int k = 0; k < 16; ++k) {
                acc[k] += __shfl_xor(acc[k], 16, 64);
                acc[k] += __shfl_xor(acc[k], 32, 64);
            }
            // bias + relu (channels ch*16 + k)
#pragma unroll
            for (int k = 0; k < 16; ++k)
                acc[k] = fmaxf(acc[k] + bias[ch * 16 + k], 0.f);
        }

        // pack a1 -> bf16 frag and write swizzled LDS (eg0: octet 2ch, eg1: 2ch+1)
        if (eg < 2) {
            s16x8 v;
            int base = eg * 8;
#pragma unroll
            for (int k = 0; k < 8; ++k) v[k] = f2bf(acc[base + k]);
            int o = 2 * ch + eg;                 // octet 0..31
            int c = o >> 2, q = o & 3;
            int slot = q * 16 + ((r + q + ((c & 3) << 2)) & 15);
            As[c * 64 + slot] = v;
        }
    }
    __syncthreads();

    // ---- phase 2: h2 = a1 @ Wt2 (K=256 -> KC=8; wave w -> col tiles 2w, 2w+1) ----
    const int q = lane >> 4;
    const int rl = lane & 15;
    const s16x8* wt = (const s16x8*)Wt2;

    f32x4 acc2[2];
    acc2[0] = (f32x4){0.f, 0.f, 0.f, 0.f};
    acc2[1] = (f32x4){0.f, 0.f, 0.f, 0.f};

#pragma unroll
    for (int c = 0; c < 8; ++c) {
        int slot = q * 16 + ((rl + q + ((c & 3) << 2)) & 15);
        b16x8 areg = __builtin_bit_cast(b16x8, As[c * 64 + slot]);
        size_t bb = (size_t)c * 512 + (wave * 2) * 64 + lane;
        b16x8 b0 = __builtin_bit_cast(b16x8, wt[bb]);
        b16x8 b1 = __builtin_bit_cast(b16x8, wt[bb + 64]);
        acc2[0] = __builtin_amdgcn_mfma_f32_16x16x32_bf16(areg, b0, acc2[0], 0, 0, 0);
        acc2[1] = __builtin_amdgcn_mfma_f32_16x16x32_bf16(areg, b1, acc2[1], 0, 0, 0);
    }

    const int quad = lane >> 4;
    const int nl = lane & 15;
#pragma unroll
    for (int j = 0; j < 2; ++j) {
        int col = (wave * 2 + j) * 16 + nl;
#pragma unroll
        for (int rr = 0; rr < 4; ++rr) {
            int row = nb0 + quad * 4 + rr;
            if (row < n) {
                unsigned u = __builtin_amdgcn_cvt_pk_fp8_f32(acc2[j][rr], acc2[j][rr], 0, false);
                h2[(size_t)row * 128 + col] = (unsigned char)(u & 0xFF);
            }
        }
    }
}

// Layer 2 agg fused with W3: h2 fp8 (128 B rows), 4-edge-parallel; a2 = relu(agg+b2);
// z = a2 @ W3 (128x2) via per-lane partials + shuffle reduce.
__global__ __launch_bounds__(256) void agg128_w3_kernel(const unsigned char* __restrict__ h,
                                                        const int* __restrict__ rp,
                                                        const int2* __restrict__ ecw,
                                                        const float* __restrict__ dinv,
                                                        const float* __restrict__ b2,
                                                        const float* __restrict__ W3,
                                                        float* __restrict__ z, int n) {
    int node = blockIdx.x * 4 + (threadIdx.x >> 6);
    int lane = threadIdx.x & 63;
    if (node >= n) return;
    const int eg = lane >> 4;                    // edge slot 0..3
    const int ch = lane & 15;                    // 8B chunk (8 fp8 channels)
    float di = dinv[node];

    float acc[8];
    {
        u32x2 v = *(const u32x2*)(h + (size_t)node * 128 + ch * 8);
        float ws = (eg == 0) ? di * di : 0.f;
        f32x2 l0 = __builtin_amdgcn_cvt_pk_f32_fp8(v.x, false);
        f32x2 h0 = __builtin_amdgcn_cvt_pk_f32_fp8(v.x, true);
        f32x2 l1 = __builtin_amdgcn_cvt_pk_f32_fp8(v.y, false);
        f32x2 h1 = __builtin_amdgcn_cvt_pk_f32_fp8(v.y, true);
        acc[0] = ws * l0.x; acc[1] = ws * l0.y; acc[2] = ws * h0.x; acc[3] = ws * h0.y;
        acc[4] = ws * l1.x; acc[5] = ws * l1.y; acc[6] = ws * h1.x; acc[7] = ws * h1.y;
    }

    int e0 = rp[node], e1 = rp[node + 1];
    for (int base = e0; base < e1; base += 64) {
        int idx = base + lane;
        int2 er = (idx < e1) ? ecw[idx] : make_int2(0, 0);
        int sb = er.x;
        float wb = __int_as_float(er.y);
        int cnt = e1 - base; if (cnt > 64) cnt = 64;
#pragma unroll 4
        for (int i = 0; i < cnt; i += 4) {
            int s = __shfl(sb, i + eg, 64);
            float w = __shfl(wb, i + eg, 64);
            u32x2 v = *(const u32x2*)(h + (size_t)s * 128 + ch * 8);
            f32x2 l0 = __builtin_amdgcn_cvt_pk_f32_fp8(v.x, false);
            f32x2 h0 = __builtin_amdgcn_cvt_pk_f32_fp8(v.x, true);
            f32x2 l1 = __builtin_amdgcn_cvt_pk_f32_fp8(v.y, false);
            f32x2 h1 = __builtin_amdgcn_cvt_pk_f32_fp8(v.y, true);
            acc[0] += w * l0.x; acc[1] += w * l0.y; acc[2] += w * h0.x; acc[3] += w * h0.y;
            acc[4] += w * l1.x; acc[5] += w * l1.y; acc[6] += w * h1.x; acc[7] += w * h1.y;
        }
    }

#pragma unroll
    for (int k = 0; k < 8; ++k) {
        acc[k] += __shfl_xor(acc[k], 16, 64);
        acc[k] += __shfl_xor(acc[k], 32, 64);
    }

    // a2 = relu(acc + b2); z partials over this lane's 8 channels
    float z0 = 0.f, z1 = 0.f;
#pragma unroll
    for (int k = 0; k < 8; ++k) {
        float a = fmaxf(acc[k] + b2[ch * 8 + k], 0.f);
        z0 += a * W3[(ch * 8 + k) * 2];
        z1 += a * W3[(ch * 8 + k) * 2 + 1];
    }
    // reduce over the 16 ch groups (all eg groups hold identical values)
    for (int off = 8; off > 0; off >>= 1) {
        z0 += __shfl_xor(z0, off, 64);
        z1 += __shfl_xor(z1, off, 64);
    }
    if (lane == 0) {
        z[2 * (size_t)node] = z0;
        z[2 * (size_t)node + 1] = z1;
    }
}

// agg3: wave per node, 64-lane edge-parallel gather of z pairs + xor-tree reduce.
__global__ __launch_bounds__(256) void agg3_kernel(const float* __restrict__ z,
                                                   const int* __restrict__ rp,
                                                   const int2* __restrict__ ecw,
                                                   const float* __restrict__ dinv,
                                                   const float* __restrict__ bias,
                                                   float* __restrict__ out, int n) {
    int node = blockIdx.x * 4 + (threadIdx.x >> 6);
    int lane = threadIdx.x & 63;
    if (node >= n) return;
    float a0 = 0.f, a1 = 0.f;
    int e0 = rp[node], e1 = rp[node + 1];
    for (int idx = e0 + lane; idx < e1; idx += 64) {
        int2 er = ecw[idx];
        float w = __int_as_float(er.y);
        float2 zz = *(const float2*)(z + 2 * (size_t)er.x);
        a0 += w * zz.x;
        a1 += w * zz.y;
    }
    for (int off = 32; off > 0; off >>= 1) {
        a0 += __shfl_xor(a0, off, 64);
        a1 += __shfl_xor(a1, off, 64);
    }
    if (lane == 0) {
        float di = dinv[node];
        float2 zn = *(const float2*)(z + 2 * (size_t)node);
        a0 += di * di * zn.x + bias[0];
        a1 += di * di * zn.y + bias[1];
        out[2 * (size_t)node]     = 1.f / (1.f + __expf(-a0));
        out[2 * (size_t)node + 1] = 1.f / (1.f + __expf(-a1));
    }
}

// ---------------- launch ----------------

extern "C" void kernel_launch(void* const* d_in, const int* in_sizes, int n_in,
                              void* d_out, int out_size, void* d_ws, size_t ws_size,
                              hipStream_t stream) {
    const float* x  = (const float*)d_in[0];
    const int*   ei = (const int*)d_in[1];
    const float* W1 = (const float*)d_in[2];
    const float* b1 = (const float*)d_in[3];
    const float* W2 = (const float*)d_in[4];
    const float* b2 = (const float*)d_in[5];
    const float* W3 = (const float*)d_in[6];
    const float* b3 = (const float*)d_in[7];
    float* out = (float*)d_out;

    const int E  = in_sizes[1] / 2;
    const int C1 = in_sizes[3];              // 256
    const int C2 = in_sizes[5];              // 128
    const int K1 = in_sizes[2] / C1;         // 768
    const int N  = in_sizes[0] / K1;         // 50000

    const int* srcv = ei;
    const int* dstv = ei + E;

    char* p = (char*)d_ws;
    auto carve = [&](size_t bytes) {
        char* r = p;
        p += (bytes + 255) & ~(size_t)255;
        return r;
    };
    // cnt and bsum adjacent so one memset zeroes both (bsum sentinel = 0)
    int*   cnt    = (int*)carve((size_t)N * 4);
    int*   bsum   = (int*)carve(1024 * 4);
    int*   rp     = (int*)carve((size_t)(N + 1) * 4);
    int*   cursor = (int*)carve((size_t)N * 4);
    float* dinv   = (float*)carve((size_t)N * 4);
    int2*  ecw    = (int2*)carve((size_t)E * 8);                     // packed {src, w}
    short* Wt1    = (short*)carve((size_t)K1 * C1 * 2);
    short* Wt2    = (short*)carve((size_t)C1 * C2 * 2);
    unsigned char* h8 = (unsigned char*)carve((size_t)N * C1);       // fp8 h1
    unsigned char* h2 = (unsigned char*)carve((size_t)N * C2);       // fp8 h2
    float* zbuf   = (float*)carve((size_t)N * 2 * 4);

    const int nb  = (N + 1023) / 1024;       // scan blocks (49)
    const int cb  = (E + 255) / 256;         // count blocks
    const int w1b = (K1 * C1) / 1024;        // 192 wt1 blocks (1024 thr)
    const int w2b = (C1 * C2) / 1024;        // 32 wt2 blocks
    const int g1b = (N + 31) / 32;           // gemm1 blocks
    const int fb  = (E + 255) / 256;         // fill blocks

    // zero cnt + bsum sentinels in one memset (adjacent carves)
    size_t cntpad = (((size_t)N * 4) + 255) & ~(size_t)255;
    hipMemsetAsync(cnt, 0, cntpad + 1024 * 4, stream);
    count_kernel<<<cb, 256, 0, stream>>>(dstv, cnt, E);
    // fused scan+fixup (device-scope published totals) + Wt1/Wt2 conversion
    scanfix_kernel<<<nb + w1b + w2b, 1024, 0, stream>>>(cnt, rp, cursor, dinv, bsum,
                                                        N, E, nb, W1, Wt1, W2, Wt2, w1b);

    // Layer 1 GEMM fused with CSR fill (interleaved roles, one launch)
    gemm1_fill_kernel<<<g1b + fb, 256, 0, stream>>>(x, Wt1, h8, N, g1b, fb,
                                                    srcv, dstv, cursor, dinv, ecw, E);

    // Layer 1 aggregation fused with layer-2 GEMM: a1 = relu(Ahat h1 + b1) staged to
    // frag-ready LDS, h2 = a1 @ W2 (fp8 out). hB buffer and gemm_panel launch gone.
    agg256_g2_kernel<<<(N + 15) / 16, 256, 0, stream>>>(h8, rp, ecw, dinv, b1, Wt2, h2, N);

    // Layer 2 aggregation fused with W3: a2 = relu(agg+b2), z = a2 @ W3
    agg128_w3_kernel<<<(N + 3) / 4, 256, 0, stream>>>(h2, rp, ecw, dinv, b2, W3, zbuf, N);

    // Layer 3 aggregation + sigmoid (wave-parallel)
    agg3_kernel<<<(N + 3) / 4, 256, 0, stream>>>(zbuf, rp, ecw, dinv, b3, out, N);
}

// Round 15
// 412.979 us; speedup vs baseline: 1.0152x; 1.0152x over previous
//
#include <hip/hip_runtime.h>
#include <math.h>

typedef short s16x8 __attribute__((ext_vector_type(8)));
typedef __bf16 b16x8 __attribute__((ext_vector_type(8)));
typedef float f32x4 __attribute__((ext_vector_type(4)));
typedef float f32x2 __attribute__((ext_vector_type(2)));
typedef unsigned int u32x4 __attribute__((ext_vector_type(4)));
typedef unsigned int u32x2 __attribute__((ext_vector_type(2)));

__device__ inline short f2bf(float f) {
    unsigned u = __float_as_uint(f);
    unsigned r = u + 0x7FFFu + ((u >> 16) & 1u);   // RNE
    return (short)(r >> 16);
}

// ---------------- count (CSR degree) ----------------

__global__ void count_kernel(const int* __restrict__ dst, int* __restrict__ cnt, int E) {
    int e = blockIdx.x * 256 + threadIdx.x;
    if (e < E) atomicAdd(&cnt[dst[e]], 1);
}

// ---------------- fused scan + fixup + weight conversion ----------------
// Blocks [0, SB): single-pass scan with device-scope published block totals.
// Blocks [SB, ...): Wt1/Wt2 frag-layout conversion (1024-thread roles).
// Wt chunk layout: [c = k0/32][b = n0/128][nt 0..7][lane 0..63][j 0..7]
//   value = W[c*32 + (lane>>4)*8 + j][b*128 + nt*16 + (lane&15)]

__device__ inline void make_wt_elem(const float* __restrict__ W, short* __restrict__ Wt,
                                    int K, int N, int idx) {
    int NB = N >> 7;
    int j = idx & 7;
    int l = (idx >> 3) & 63;
    int nt = (idx >> 9) & 7;
    int rest = idx >> 12;
    int b = rest % NB;
    int c = rest / NB;
    int k = c * 32 + (l >> 4) * 8 + j;
    int n = b * 128 + nt * 16 + (l & 15);
    Wt[idx] = f2bf(W[(size_t)k * N + n]);
}

__global__ __launch_bounds__(1024) void scanfix_kernel(
        const int* __restrict__ cnt, int* __restrict__ rp, int* __restrict__ cursor,
        float* __restrict__ dinv, int* __restrict__ bsum, int n, int E, int SB,
        const float* __restrict__ W1, short* __restrict__ Wt1,
        const float* __restrict__ W2, short* __restrict__ Wt2, int w1b) {
    int tid = threadIdx.x;
    if (blockIdx.x >= SB) {                    // ---- weight-conversion role ----
        int b = blockIdx.x - SB;
        if (b < w1b) {
            int idx = b * 1024 + tid;
            make_wt_elem(W1, Wt1, 768, 256, idx);
        } else {
            int idx = (b - w1b) * 1024 + tid;
            make_wt_elem(W2, Wt2, 256, 128, idx);
        }
        return;
    }

    // ---- scan role ----
    __shared__ int sdata[1024];
    __shared__ int parts[64];
    __shared__ int carry_s;
    int i = blockIdx.x * 1024 + tid;
    int v = (i < n) ? cnt[i] : 0;
    sdata[tid] = v;
    __syncthreads();
    for (int off = 1; off < 1024; off <<= 1) {
        int t = 0;
        if (tid >= off) t = sdata[tid - off];
        __syncthreads();
        sdata[tid] += t;
        __syncthreads();
    }
    if (tid == 1023)
        __hip_atomic_store(&bsum[blockIdx.x], sdata[1023] + 1,
                           __ATOMIC_RELEASE, __HIP_MEMORY_SCOPE_AGENT);
    int part = 0;
    if (tid < blockIdx.x) {                    // lanes 0..47 of wave 0 (SB <= 49)
        int b;
        while ((b = __hip_atomic_load(&bsum[tid], __ATOMIC_ACQUIRE,
                                      __HIP_MEMORY_SCOPE_AGENT)) == 0) {}
        part = b - 1;
    }
    if (tid < 64) parts[tid] = part;
    __syncthreads();
    if (tid == 0) {
        int c = 0;
        for (int k = 0; k < 64; ++k) c += parts[k];
        carry_s = c;
    }
    __syncthreads();
    int r = sdata[tid] - v + carry_s;          // exclusive prefix + carry
    if (i < n) {
        rp[i] = r;
        cursor[i] = r;
        dinv[i] = rsqrtf((float)cnt[i] + 1.0f);
    }
    if (i == 0) rp[n] = E;
}

// ---------------- fused GEMM1 + fill (interleaved roles) ----------------
// Roles interleaved by block index via Bresenham proportional mapping.

__global__ __launch_bounds__(256, 3) void gemm1_fill_kernel(
        const float* __restrict__ x, const short* __restrict__ Wt,
        unsigned char* __restrict__ h8, int M, int G1B, int FB,
        const int* __restrict__ src, const int* __restrict__ dst,
        int* __restrict__ cursor, const float* __restrict__ dinv,
        int2* __restrict__ ecw, int E) {
    constexpr int KC = 24;                     // 768 / 32
    constexpr int RT = 2;                      // row-tiles -> 32 rows per block
    constexpr int O = KC * 4;                  // 96 octets (8 k-elems) per row
    constexpr int F = KC * RT * 64 / 256;      // 12 frags staged per thread

    __shared__ s16x8 As[KC * RT * 64];         // 48 KB bf16, fragment-ready

    const int tid = threadIdx.x;
    const int total = G1B + FB;
    const long long bi = (long long)blockIdx.x;
    const int fid  = (int)(bi * FB / total);
    const int fid1 = (int)((bi + 1) * FB / total);

    if (fid1 > fid) {                          // ---- fill role ----
        int e = fid * 256 + tid;
        if (e < E) {
            int d = dst[e];
            int s = src[e];
            int p = atomicAdd(&cursor[d], 1);
            ecw[p] = make_int2(s, __float_as_int(dinv[s] * dinv[d]));
        }
        return;
    }
    const int gid = blockIdx.x - fid;          // gemm1 block id, 0..G1B-1

    // ---- gemm1 role ----
    const int m0 = gid * (RT * 16);

    // stage: load fp32 pairs, truncation-pack to bf16
    s16x8 v[F];
#pragma unroll
    for (int i = 0; i < F; ++i) {
        int idx = i * 256 + tid;
        int r = idx / O;
        int o = idx - r * O;
        int row = m0 + r;
        if (row >= M) row = M - 1;
        const float4* fp = (const float4*)(x + (size_t)row * 768 + o * 8);
        float4 f0 = fp[0];
        float4 f1 = fp[1];
        u32x4 pk;
        pk.x = (__float_as_uint(f0.x) >> 16) | (__float_as_uint(f0.y) & 0xFFFF0000u);
        pk.y = (__float_as_uint(f0.z) >> 16) | (__float_as_uint(f0.w) & 0xFFFF0000u);
        pk.z = (__float_as_uint(f1.x) >> 16) | (__float_as_uint(f1.y) & 0xFFFF0000u);
        pk.w = (__float_as_uint(f1.z) >> 16) | (__float_as_uint(f1.w) & 0xFFFF0000u);
        v[i] = __builtin_bit_cast(s16x8, pk);
    }
#pragma unroll
    for (int i = 0; i < F; ++i) {
        int idx = i * 256 + tid;
        int r = idx / O;
        int o = idx - r * O;
        int c = o >> 2, q = o & 3;
        int slot = q * 16 + (((r & 15) + q + ((c & 3) << 2)) & 15);
        As[(c * RT + (r >> 4)) * 64 + slot] = v[i];
    }
    __syncthreads();

    const int lane = tid & 63;
    const int wave = tid >> 6;
    const int b128 = wave >> 1;                // 128-col B block
    const int nt0 = (wave & 1) * 4;            // first 16-col tile inside it
    const int q = lane >> 4;
    const int rl = lane & 15;
    const s16x8* wt = (const s16x8*)Wt;

    f32x4 acc[RT][4];
#pragma unroll
    for (int i = 0; i < RT; ++i)
#pragma unroll
        for (int j = 0; j < 4; ++j)
            acc[i][j] = (f32x4){0.f, 0.f, 0.f, 0.f};

#pragma unroll 4
    for (int c = 0; c < KC; ++c) {
        int slot = q * 16 + ((rl + q + ((c & 3) << 2)) & 15);
        b16x8 areg[RT], breg[4];
#pragma unroll
        for (int i = 0; i < RT; ++i)
            areg[i] = __builtin_bit_cast(b16x8, As[(c * RT + i) * 64 + slot]);
        size_t bb = (size_t)(c * 2 + b128) * 512 + nt0 * 64 + lane;
#pragma unroll
        for (int j = 0; j < 4; ++j)
            breg[j] = __builtin_bit_cast(b16x8, wt[bb + j * 64]);
#pragma unroll
        for (int i = 0; i < RT; ++i)
#pragma unroll
            for (int j = 0; j < 4; ++j)
                acc[i][j] = __builtin_amdgcn_mfma_f32_16x16x32_bf16(areg[i], breg[j], acc[i][j], 0, 0, 0);
    }

    const int quad = lane >> 4;
    const int nl = lane & 15;
#pragma unroll
    for (int i = 0; i < RT; ++i) {
        int rbase = m0 + i * 16 + quad * 4;
#pragma unroll
        for (int j = 0; j < 4; ++j) {
            int col = wave * 64 + j * 16 + nl;
#pragma unroll
            for (int r = 0; r < 4; ++r) {
                int row = rbase + r;
                if (row < M) {
                    unsigned u = __builtin_amdgcn_cvt_pk_fp8_f32(acc[i][j][r], acc[i][j][r], 0, false);
                    h8[(size_t)row * 256 + col] = (unsigned char)(u & 0xFF);
                }
            }
        }
    }
}

// ---------------- fused layer-1 aggregation + layer-2 GEMM (v2: wave-per-node) ----------------
// Block = 1024 threads = 16 waves; wave w gathers node nb0+w with the EXACT champion
// 4-edge-parallel structure (50000 waves total — same parallelism as the standalone
// agg256). a1 packed (f2bf, identical bits to the old hB path) into the proven
// frag-ready swizzled LDS layout (RT=1, r = wave). One barrier. Phase 2: waves 0..7
// each compute one 16-col tile of h2 = a1 @ Wt2 (8 MFMAs, same K-order and B frags
// as gemm_panel -> bit-identical h2); waves 8..15 exit. Kills the gemm_panel launch
// and the 51 MB hB round-trip. launch_bounds(1024,8) caps VGPR at 64 -> 2 blocks/CU.

__global__ __launch_bounds__(1024, 8) void agg256_g2_kernel(
        const unsigned char* __restrict__ h8, const int* __restrict__ rp,
        const int2* __restrict__ ecw, const float* __restrict__ dinv,
        const float* __restrict__ bias, const short* __restrict__ Wt2,
        unsigned char* __restrict__ h2, int n) {
    __shared__ s16x8 As[8 * 64];               // 16 rows x 256 ch bf16, frag-ready (8 KB)

    const int tid = threadIdx.x;
    const int lane = tid & 63;
    const int wave = tid >> 6;                   // 0..15 = row r
    const int eg = lane >> 4;                    // edge slot 0..3
    const int ch = lane & 15;                    // 16-channel chunk
    const int nb0 = blockIdx.x * 16;
    const int node = nb0 + wave;

    float acc[16];
#pragma unroll
    for (int k = 0; k < 16; ++k) acc[k] = 0.f;

    if (node < n) {
        float di = dinv[node];
        {
            u32x4 v = *(const u32x4*)(h8 + (size_t)node * 256 + ch * 16);
            float ws = (eg == 0) ? di * di : 0.f;    // self term counted once
#pragma unroll
            for (int u = 0; u < 4; ++u) {
                f32x2 lo = __builtin_amdgcn_cvt_pk_f32_fp8(v[u], false);
                f32x2 hi = __builtin_amdgcn_cvt_pk_f32_fp8(v[u], true);
                acc[u * 4 + 0] = ws * lo.x; acc[u * 4 + 1] = ws * lo.y;
                acc[u * 4 + 2] = ws * hi.x; acc[u * 4 + 3] = ws * hi.y;
            }
        }
        int e0 = rp[node], e1 = rp[node + 1];
        for (int base = e0; base < e1; base += 64) {
            int idx = base + lane;
            int2 er = (idx < e1) ? ecw[idx] : make_int2(0, 0);
            int sb = er.x;
            float wb = __int_as_float(er.y);
            int cnt = e1 - base; if (cnt > 64) cnt = 64;
#pragma unroll 4
            for (int i = 0; i < cnt; i += 4) {
                int s = __shfl(sb, i + eg, 64);   // i+eg <= 63 (i step 4, i<=60)
                float w = __shfl(wb, i + eg, 64);
                u32x4 v = *(const u32x4*)(h8 + (size_t)s * 256 + ch * 16);
#pragma unroll
                for (int u = 0; u < 4; ++u) {
                    f32x2 lo = __builtin_amdgcn_cvt_pk_f32_fp8(v[u], false);
                    f32x2 hi = __builtin_amdgcn_cvt_pk_f32_fp8(v[u], true);
                    acc[u * 4 + 0] += w * lo.x; acc[u * 4 + 1] += w * lo.y;
                    acc[u * 4 + 2] += w * hi.x; acc[u * 4 + 3] += w * hi.y;
                }
            }
        }
        // combine the 4 edge slots
#pragma unroll
        for (int k = 0; k < 16; ++k) {
            acc[k] += __shfl_xor(acc[k], 16, 64);
            acc[k] += __shfl_xor(acc[k], 32, 64);
        }
        // bias + relu (channels ch*16 + k)
#pragma unroll
        for (int k = 0; k < 16; ++k)
            acc[k] = fmaxf(acc[k] + bias[ch * 16 + k], 0.f);
    }

    // pack a1 -> bf16 frag and write swizzled LDS (eg0: octet 2ch, eg1: 2ch+1; r = wave)
    if (eg < 2) {
        s16x8 v;
        int base = eg * 8;
#pragma unroll
        for (int k = 0; k < 8; ++k) v[k] = f2bf(acc[base + k]);
        int o = 2 * ch + eg;                 // octet 0..31
        int c = o >> 2, q = o & 3;
        int slot = q * 16 + ((wave + q + ((c & 3) << 2)) & 15);
        As[c * 64 + slot] = v;
    }
    __syncthreads();

    // ---- phase 2: h2 = a1 @ Wt2 (K=256 -> KC=8); waves 0..7 -> col tile nt = wave ----
    if (wave >= 8) return;
    const int q = lane >> 4;
    const int rl = lane & 15;
    const s16x8* wt = (const s16x8*)Wt2;

    f32x4 acc2 = (f32x4){0.f, 0.f, 0.f, 0.f};
#pragma unroll
    for (int c = 0; c < 8; ++c) {
        int slot = q * 16 + ((rl + q + ((c & 3) << 2)) & 15);
        b16x8 areg = __builtin_bit_cast(b16x8, As[c * 64 + slot]);
        b16x8 breg = __builtin_bit_cast(b16x8, wt[(size_t)c * 512 + wave * 64 + lane]);
        acc2 = __builtin_amdgcn_mfma_f32_16x16x32_bf16(areg, breg, acc2, 0, 0, 0);
    }

    const int quad = lane >> 4;
    const int nl = lane & 15;
    int col = wave * 16 + nl;
#pragma unroll
    for (int rr = 0; rr < 4; ++rr) {
        int row = nb0 + quad * 4 + rr;
        if (row < n) {
            unsigned u = __builtin_amdgcn_cvt_pk_fp8_f32(acc2[rr], acc2[rr], 0, false);
            h2[(size_t)row * 128 + col] = (unsigned char)(u & 0xFF);
        }
    }
}

// Layer 2 agg fused with W3: h2 fp8 (128 B rows), 4-edge-parallel; a2 = relu(agg+b2);
// z = a2 @ W3 (128x2) via per-lane partials + shuffle reduce.
__global__ __launch_bounds__(256) void agg128_w3_kernel(const unsigned char* __restrict__ h,
                                                        const int* __restrict__ rp,
                                                        const int2* __restrict__ ecw,
                                                        const float* __restrict__ dinv,
                                                        const float* __restrict__ b2,
                                                        const float* __restrict__ W3,
                                                        float* __restrict__ z, int n) {
    int node = blockIdx.x * 4 + (threadIdx.x >> 6);
    int lane = threadIdx.x & 63;
    if (node >= n) return;
    const int eg = lane >> 4;                    // edge slot 0..3
    const int ch = lane & 15;                    // 8B chunk (8 fp8 channels)
    float di = dinv[node];

    float acc[8];
    {
        u32x2 v = *(const u32x2*)(h + (size_t)node * 128 + ch * 8);
        float ws = (eg == 0) ? di * di : 0.f;
        f32x2 l0 = __builtin_amdgcn_cvt_pk_f32_fp8(v.x, false);
        f32x2 h0 = __builtin_amdgcn_cvt_pk_f32_fp8(v.x, true);
        f32x2 l1 = __builtin_amdgcn_cvt_pk_f32_fp8(v.y, false);
        f32x2 h1 = __builtin_amdgcn_cvt_pk_f32_fp8(v.y, true);
        acc[0] = ws * l0.x; acc[1] = ws * l0.y; acc[2] = ws * h0.x; acc[3] = ws * h0.y;
        acc[4] = ws * l1.x; acc[5] = ws * l1.y; acc[6] = ws * h1.x; acc[7] = ws * h1.y;
    }

    int e0 = rp[node], e1 = rp[node + 1];
    for (int base = e0; base < e1; base += 64) {
        int idx = base + lane;
        int2 er = (idx < e1) ? ecw[idx] : make_int2(0, 0);
        int sb = er.x;
        float wb = __int_as_float(er.y);
        int cnt = e1 - base; if (cnt > 64) cnt = 64;
#pragma unroll 4
        for (int i = 0; i < cnt; i += 4) {
            int s = __shfl(sb, i + eg, 64);
            float w = __shfl(wb, i + eg, 64);
            u32x2 v = *(const u32x2*)(h + (size_t)s * 128 + ch * 8);
            f32x2 l0 = __builtin_amdgcn_cvt_pk_f32_fp8(v.x, false);
            f32x2 h0 = __builtin_amdgcn_cvt_pk_f32_fp8(v.x, true);
            f32x2 l1 = __builtin_amdgcn_cvt_pk_f32_fp8(v.y, false);
            f32x2 h1 = __builtin_amdgcn_cvt_pk_f32_fp8(v.y, true);
            acc[0] += w * l0.x; acc[1] += w * l0.y; acc[2] += w * h0.x; acc[3] += w * h0.y;
            acc[4] += w * l1.x; acc[5] += w * l1.y; acc[6] += w * h1.x; acc[7] += w * h1.y;
        }
    }

#pragma unroll
    for (int k = 0; k < 8; ++k) {
        acc[k] += __shfl_xor(acc[k], 16, 64);
        acc[k] += __shfl_xor(acc[k], 32, 64);
    }

    // a2 = relu(acc + b2); z partials over this lane's 8 channels
    float z0 = 0.f, z1 = 0.f;
#pragma unroll
    for (int k = 0; k < 8; ++k) {
        float a = fmaxf(acc[k] + b2[ch * 8 + k], 0.f);
        z0 += a * W3[(ch * 8 + k) * 2];
        z1 += a * W3[(ch * 8 + k) * 2 + 1];
    }
    // reduce over the 16 ch groups (all eg groups hold identical values)
    for (int off = 8; off > 0; off >>= 1) {
        z0 += __shfl_xor(z0, off, 64);
        z1 += __shfl_xor(z1, off, 64);
    }
    if (lane == 0) {
        z[2 * (size_t)node] = z0;
        z[2 * (size_t)node + 1] = z1;
    }
}

// agg3: wave per node, 64-lane edge-parallel gather of z pairs + xor-tree reduce.
__global__ __launch_bounds__(256) void agg3_kernel(const float* __restrict__ z,
                                                   const int* __restrict__ rp,
                                                   const int2* __restrict__ ecw,
                                                   const float* __restrict__ dinv,
                                                   const float* __restrict__ bias,
                                                   float* __restrict__ out, int n) {
    int node = blockIdx.x * 4 + (threadIdx.x >> 6);
    int lane = threadIdx.x & 63;
    if (node >= n) return;
    float a0 = 0.f, a1 = 0.f;
    int e0 = rp[node], e1 = rp[node + 1];
    for (int idx = e0 + lane; idx < e1; idx += 64) {
        int2 er = ecw[idx];
        float w = __int_as_float(er.y);
        float2 zz = *(const float2*)(z + 2 * (size_t)er.x);
        a0 += w * zz.x;
        a1 += w * zz.y;
    }
    for (int off = 32; off > 0; off >>= 1) {
        a0 += __shfl_xor(a0, off, 64);
        a1 += __shfl_xor(a1, off, 64);
    }
    if (lane == 0) {
        float di = dinv[node];
        float2 zn = *(const float2*)(z + 2 * (size_t)node);
        a0 += di * di * zn.x + bias[0];
        a1 += di * di * zn.y + bias[1];
        out[2 * (size_t)node]     = 1.f / (1.f + __expf(-a0));
        out[2 * (size_t)node + 1] = 1.f / (1.f + __expf(-a1));
    }
}

// ---------------- launch ----------------

extern "C" void kernel_launch(void* const* d_in, const int* in_sizes, int n_in,
                              void* d_out, int out_size, void* d_ws, size_t ws_size,
                              hipStream_t stream) {
    const float* x  = (const float*)d_in[0];
    const int*   ei = (const int*)d_in[1];
    const float* W1 = (const float*)d_in[2];
    const float* b1 = (const float*)d_in[3];
    const float* W2 = (const float*)d_in[4];
    const float* b2 = (const float*)d_in[5];
    const float* W3 = (const float*)d_in[6];
    const float* b3 = (const float*)d_in[7];
    float* out = (float*)d_out;

    const int E  = in_sizes[1] / 2;
    const int C1 = in_sizes[3];              // 256
    const int C2 = in_sizes[5];              // 128
    const int K1 = in_sizes[2] / C1;         // 768
    const int N  = in_sizes[0] / K1;         // 50000

    const int* srcv = ei;
    const int* dstv = ei + E;

    char* p = (char*)d_ws;
    auto carve = [&](size_t bytes) {
        char* r = p;
        p += (bytes + 255) & ~(size_t)255;
        return r;
    };
    // cnt and bsum adjacent so one memset zeroes both (bsum sentinel = 0)
    int*   cnt    = (int*)carve((size_t)N * 4);
    int*   bsum   = (int*)carve(1024 * 4);
    int*   rp     = (int*)carve((size_t)(N + 1) * 4);
    int*   cursor = (int*)carve((size_t)N * 4);
    float* dinv   = (float*)carve((size_t)N * 4);
    int2*  ecw    = (int2*)carve((size_t)E * 8);                     // packed {src, w}
    short* Wt1    = (short*)carve((size_t)K1 * C1 * 2);
    short* Wt2    = (short*)carve((size_t)C1 * C2 * 2);
    unsigned char* h8 = (unsigned char*)carve((size_t)N * C1);       // fp8 h1
    unsigned char* h2 = (unsigned char*)carve((size_t)N * C2);       // fp8 h2
    float* zbuf   = (float*)carve((size_t)N * 2 * 4);

    const int nb  = (N + 1023) / 1024;       // scan blocks (49)
    const int cb  = (E + 255) / 256;         // count blocks
    const int w1b = (K1 * C1) / 1024;        // 192 wt1 blocks (1024 thr)
    const int w2b = (C1 * C2) / 1024;        // 32 wt2 blocks
    const int g1b = (N + 31) / 32;           // gemm1 blocks
    const int fb  = (E + 255) / 256;         // fill blocks

    // zero cnt + bsum sentinels in one memset (adjacent carves)
    size_t cntpad = (((size_t)N * 4) + 255) & ~(size_t)255;
    hipMemsetAsync(cnt, 0, cntpad + 1024 * 4, stream);
    count_kernel<<<cb, 256, 0, stream>>>(dstv, cnt, E);
    // fused scan+fixup (device-scope published totals) + Wt1/Wt2 conversion
    scanfix_kernel<<<nb + w1b + w2b, 1024, 0, stream>>>(cnt, rp, cursor, dinv, bsum,
                                                        N, E, nb, W1, Wt1, W2, Wt2, w1b);

    // Layer 1 GEMM fused with CSR fill (interleaved roles, one launch)
    gemm1_fill_kernel<<<g1b + fb, 256, 0, stream>>>(x, Wt1, h8, N, g1b, fb,
                                                    srcv, dstv, cursor, dinv, ecw, E);

    // Layer 1 aggregation fused with layer-2 GEMM (wave-per-node, 16 waves/block):
    // a1 = relu(Ahat h1 + b1) -> frag LDS -> h2 = a1 @ W2 (fp8 out).
    agg256_g2_kernel<<<(N + 15) / 16, 1024, 0, stream>>>(h8, rp, ecw, dinv, b1, Wt2, h2, N);

    // Layer 2 aggregation fused with W3: a2 = relu(agg+b2), z = a2 @ W3
    agg128_w3_kernel<<<(N + 3) / 4, 256, 0, stream>>>(h2, rp, ecw, dinv, b2, W3, zbuf, N);

    // Layer 3 aggregation + sigmoid (wave-parallel)
    agg3_kernel<<<(N + 3) / 4, 256, 0, stream>>>(zbuf, rp, ecw, dinv, b3, out, N);
}